// Round 5
// baseline (77.559 us; speedup 1.0000x reference)
//
#include <hip/hip_runtime.h>
#include <stdint.h>

typedef _Float16 f16x8 __attribute__((ext_vector_type(8)));
typedef float f32x4 __attribute__((ext_vector_type(4)));

__device__ __forceinline__ uint32_t pack2(float a, float b) {
    union { _Float16 h[2]; uint32_t u; } p;
    p.h[0] = (_Float16)a; p.h[1] = (_Float16)b;
    return p.u;
}

__device__ __forceinline__ f32x4 MF(f16x8 a, f16x8 b, f32x4 c) {
    return __builtin_amdgcn_mfma_f32_16x16x32_f16(a, b, c, 0, 0, 0);
}

// Gram accumulate over one 128-t chunk held in bp (64 rows x 256 B, swizzled).
// mfma(fr[tj], fr[ti]) -> lane holds G[ti*16+l4][tj*16+lg*4+reg]
__device__ __forceinline__ void gram_chunk(const unsigned char* bp, f32x4 dd[2][4],
                                           int l4, int lg, int hi) {
    #pragma unroll
    for (int ks = 0; ks < 4; ++ks) {
        f16x8 fr[4];
        #pragma unroll
        for (int i2 = 0; i2 < 4; ++i2)
            fr[i2] = *(const f16x8*)(bp + (i2 * 16 + l4) * 256 +
                                     ((ks * 64 + lg * 16) ^ ((l4 & 7) << 4)));
        if (!hi) {
            #pragma unroll
            for (int tj = 0; tj < 4; ++tj) {
                dd[0][tj] = MF(fr[tj], fr[0], dd[0][tj]);
                dd[1][tj] = MF(fr[tj], fr[1], dd[1][tj]);
            }
        } else {
            #pragma unroll
            for (int tj = 0; tj < 4; ++tj) {
                dd[0][tj] = MF(fr[tj], fr[2], dd[0][tj]);
                dd[1][tj] = MF(fr[tj], fr[3], dd[1][tj]);
            }
        }
    }
}

__global__ __launch_bounds__(512, 4)
void gfc_main(const float* __restrict__ X, const float* __restrict__ gp,
              float* __restrict__ out) {
    // 64 KB: 4 f-slices x (64 c-rows x 256 B) -- one 128-t chunk, f16, swizzled
    __shared__ __align__(16) unsigned char XS[65536];
    __shared__ float Rbuf[4][64];

    // XCD swizzle: 4 sibling f-quads of one (n, 16-f line group) share an XCD
    int j = blockIdx.x;
    int xcd = j & 7, s = j >> 3;
    int gi = s >> 2, fq4 = s & 3;
    int g = gi * 8 + xcd;
    int n = g >> 2, f16g = g & 3;
    int f0 = f16g * 16 + fq4 * 4;

    int tid = threadIdx.x;
    int wid = tid >> 6, lane = tid & 63;
    int w4 = wid & 3, hi = wid >> 2;     // f within quad; row-half of C
    int l4 = lane & 15, lg = lane >> 4;

    float p10 = exp2f(gp[0] * 3.3219280948873623f);   // 10^gammad

    const float* Xn = X + (size_t)n * 1048576 + f0;

    f32x4 dd[2][4];
    #pragma unroll
    for (int a = 0; a < 2; ++a)
        #pragma unroll
        for (int b = 0; b < 4; ++b) dd[a][b] = f32x4{0, 0, 0, 0};

    // ---- stage chunk0: all 16 float4 loads in flight, then pack+write ----
    {
        float4 v[8][2];
        #pragma unroll
        for (int k = 0; k < 8; ++k) {
            int c = k * 8 + wid;
            const float* p = Xn + (size_t)c * 16384 + lane * 128;
            v[k][0] = *(const float4*)p;         // t = 2*lane
            v[k][1] = *(const float4*)(p + 64);  // t = 2*lane+1
        }
        #pragma unroll
        for (int k = 0; k < 8; ++k) {
            int c = k * 8 + wid;
            int o = c * 256 + ((lane * 4) ^ ((c & 7) << 4));
            *(uint32_t*)(XS + o)         = pack2(v[k][0].x, v[k][1].x);
            *(uint32_t*)(XS + 16384 + o) = pack2(v[k][0].y, v[k][1].y);
            *(uint32_t*)(XS + 32768 + o) = pack2(v[k][0].z, v[k][1].z);
            *(uint32_t*)(XS + 49152 + o) = pack2(v[k][0].w, v[k][1].w);
        }
    }

    // ---- prefetch chunk1 into registers (T14: issue early, write late) ----
    float4 pv[8][2];
    #pragma unroll
    for (int k = 0; k < 8; ++k) {
        int c = k * 8 + wid;
        const float* p = Xn + 8192 + (size_t)c * 16384 + lane * 128;
        pv[k][0] = *(const float4*)p;
        pv[k][1] = *(const float4*)(p + 64);
    }

    __syncthreads();   // B1: chunk0 LDS ready (chunk1 loads still in flight)

    gram_chunk(XS + w4 * 16384, dd, l4, lg, hi);

    __syncthreads();   // B2: chunk0 reads done, safe to overwrite

    #pragma unroll
    for (int k = 0; k < 8; ++k) {
        int c = k * 8 + wid;
        int o = c * 256 + ((lane * 4) ^ ((c & 7) << 4));
        *(uint32_t*)(XS + o)         = pack2(pv[k][0].x, pv[k][1].x);
        *(uint32_t*)(XS + 16384 + o) = pack2(pv[k][0].y, pv[k][1].y);
        *(uint32_t*)(XS + 32768 + o) = pack2(pv[k][0].z, pv[k][1].z);
        *(uint32_t*)(XS + 49152 + o) = pack2(pv[k][0].w, pv[k][1].w);
    }

    __syncthreads();   // B3: chunk1 LDS ready

    gram_chunk(XS + w4 * 16384, dd, l4, lg, hi);

    // ---- R = diag(G). Diag tiles: dd[0][2hi], dd[1][2hi+1]; lg*4+reg==l4 ----
    {
        f32x4 dg0 = hi ? dd[0][2] : dd[0][0];
        f32x4 dg1 = hi ? dd[1][3] : dd[1][1];
        if (lg == (l4 >> 2)) {
            int r = l4 & 3;
            float v0 = r == 0 ? dg0[0] : r == 1 ? dg0[1] : r == 2 ? dg0[2] : dg0[3];
            float v1 = r == 0 ? dg1[0] : r == 1 ? dg1[1] : r == 2 ? dg1[2] : dg1[3];
            Rbuf[w4][(hi * 2) * 16 + l4] = v0;
            Rbuf[w4][(hi * 2 + 1) * 16 + l4] = v1;
        }
    }
    __syncthreads();   // B4: Rbuf ready; all XS gram reads done (XS reusable)

    // ---- D = R_row + R_col - 2G in place; build 32 u16 keys ----
    float Rr0 = Rbuf[w4][(hi * 2) * 16 + l4];
    float Rr1 = Rbuf[w4][(hi * 2 + 1) * 16 + l4];
    int keys[64];
    #pragma unroll
    for (int tj = 0; tj < 4; ++tj) {
        f32x4 Rc = *(const f32x4*)&Rbuf[w4][tj * 16 + lg * 4];
        #pragma unroll
        for (int r = 0; r < 4; ++r) {
            dd[0][tj][r] = Rr0 + Rc[r] - 2.0f * dd[0][tj][r];
            dd[1][tj][r] = Rr1 + Rc[r] - 2.0f * dd[1][tj][r];
        }
    }
    #pragma unroll
    for (int tt = 0; tt < 2; ++tt) {
        int row = (hi * 2 + tt) * 16 + l4;
        #pragma unroll
        for (int tj = 0; tj < 4; ++tj)
            #pragma unroll
            for (int r = 0; r < 4; ++r) {
                int col = tj * 16 + lg * 4 + r;
                _Float16 hx = (_Float16)fmaxf(dd[tt][tj][r], 0.0f);
                uint16_t kb = __builtin_bit_cast(uint16_t, hx);
                keys[tt * 16 + tj * 4 + r] = (row < col) ? (int)kb : 0x7FFF;
            }
    }

    // ---- one-shot key exchange between the wave pair (reuses XS slice) ----
    {
        unsigned char* base = XS + w4 * 16384;
        uint16_t* mywr = (uint16_t*)(base + hi * 4096);
        #pragma unroll
        for (int e = 0; e < 32; ++e)
            mywr[e * 64 + lane] = (uint16_t)keys[e];
        __syncthreads();   // B5
        const uint16_t* prd = (const uint16_t*)(base + (hi ^ 1) * 4096);
        #pragma unroll
        for (int e = 0; e < 32; ++e)
            keys[32 + e] = (int)prd[e * 64 + lane];
    }

    // ---- exact rank-1008 select on 15-bit f16 keys (redundant per wave) ----
    int u = 0;
    for (int bit = 14; bit >= 0; --bit) {
        int cand = u | (1 << bit);
        int cnt = 0;
        #pragma unroll
        for (int i = 0; i < 64; ++i) cnt += (keys[i] < cand) ? 1 : 0;
        #pragma unroll
        for (int off = 32; off; off >>= 1) cnt += __shfl_xor(cnt, off, 64);
        if (cnt <= 1008) u = cand;
    }
    float sigma2 = (float)__builtin_bit_cast(_Float16, (uint16_t)u);
    float ninv = -1.0f / (2.0f * p10 * sigma2);

    // ---- epilogue: A = exp(-D/denom); float4 stores (4 consecutive cols) ----
    float* op = out + ((size_t)(n * 64 + f0 + w4) << 12);
    #pragma unroll
    for (int tt = 0; tt < 2; ++tt) {
        int row = (hi * 2 + tt) * 16 + l4;
        #pragma unroll
        for (int tj = 0; tj < 4; ++tj) {
            float4 rv;
            rv.x = __expf(dd[tt][tj][0] * ninv);
            rv.y = __expf(dd[tt][tj][1] * ninv);
            rv.z = __expf(dd[tt][tj][2] * ninv);
            rv.w = __expf(dd[tt][tj][3] * ninv);
            *(float4*)(op + row * 64 + tj * 16 + lg * 4) = rv;
        }
    }
}

extern "C" void kernel_launch(void* const* d_in, const int* in_sizes, int n_in,
                              void* d_out, int out_size, void* d_ws, size_t ws_size,
                              hipStream_t stream) {
    (void)in_sizes; (void)n_in; (void)out_size; (void)d_ws; (void)ws_size;
    const float* X  = (const float*)d_in[0];
    const float* gp = (const float*)d_in[1];
    float* out = (float*)d_out;
    gfc_main<<<512, 512, 0, stream>>>(X, gp, out);
}

// Round 6
// 69.343 us; speedup vs baseline: 1.1185x; 1.1185x over previous
//
#include <hip/hip_runtime.h>
#include <stdint.h>

typedef _Float16 f16x8 __attribute__((ext_vector_type(8)));
typedef float f32x4 __attribute__((ext_vector_type(4)));

#define SLICE 8192     // one f-slice in a buffer: 64 rows x 128 B (64 f16 t)
#define BUF   32768    // 4 f-slices

__device__ __forceinline__ uint32_t pack2(float a, float b) {
    union { _Float16 h[2]; uint32_t u; } p;
    p.h[0] = (_Float16)a; p.h[1] = (_Float16)b;
    return p.u;
}

__device__ __forceinline__ f32x4 MF(f16x8 a, f16x8 b, f32x4 c) {
    return __builtin_amdgcn_mfma_f32_16x16x32_f16(a, b, c, 0, 0, 0);
}

__global__ __launch_bounds__(512, 4)
void gfc_main(const float* __restrict__ X, const float* __restrict__ gp,
              float* __restrict__ out) {
    // 64 KB: two 32 KB buffers, each 4 f-slices x (64 c x 64 t f16), swizzled
    __shared__ __align__(16) unsigned char XS[2 * BUF];
    __shared__ float Rbuf[4][64];

    // XCD swizzle: 4 sibling f-quads of one (n, 16-f line group) share an XCD
    int j = blockIdx.x;
    int xcd = j & 7, s = j >> 3;
    int gi = s >> 2, fq4 = s & 3;
    int g = gi * 8 + xcd;
    int n = g >> 2, f16g = g & 3;
    int f0 = f16g * 16 + fq4 * 4;

    int tid = threadIdx.x;
    int wid = tid >> 6, lane = tid & 63;
    int w4 = wid & 3, hi = wid >> 2;     // f within quad; row-half of C
    int l4 = lane & 15, lg = lane >> 4;
    int tp = lane & 31, cs = lane >> 5;  // staging: t-pair, c-sub

    float p10 = exp2f(gp[0] * 3.3219280948873623f);   // 10^gammad
    const float* Xn = X + (size_t)n * 1048576 + f0;

    f32x4 dd[2][4];
    #pragma unroll
    for (int a = 0; a < 2; ++a)
        #pragma unroll
        for (int b = 0; b < 4; ++b) dd[a][b] = f32x4{0, 0, 0, 0};

    float4 pv[4][2];   // 32 VGPRs of in-flight chunk (spill-safe footprint)

    // -- helpers as lambdas (forced inline) --
    auto load_chunk = [&](int t0) {
        #pragma unroll
        for (int b = 0; b < 4; ++b) {
            int c = wid * 8 + b * 2 + cs;
            const float* p = Xn + ((size_t)c * 256 + t0 + 2 * tp) * 64;
            pv[b][0] = *(const float4*)p;        // t = t0+2tp
            pv[b][1] = *(const float4*)(p + 64); // t = t0+2tp+1
        }
    };
    auto write_chunk = [&](unsigned char* B) {
        #pragma unroll
        for (int b = 0; b < 4; ++b) {
            int c = wid * 8 + b * 2 + cs;
            int o = c * 128 + ((tp * 4) ^ ((c & 7) << 4));
            *(uint32_t*)(B + 0 * SLICE + o) = pack2(pv[b][0].x, pv[b][1].x);
            *(uint32_t*)(B + 1 * SLICE + o) = pack2(pv[b][0].y, pv[b][1].y);
            *(uint32_t*)(B + 2 * SLICE + o) = pack2(pv[b][0].z, pv[b][1].z);
            *(uint32_t*)(B + 3 * SLICE + o) = pack2(pv[b][0].w, pv[b][1].w);
        }
    };
    auto gram_buf = [&](const unsigned char* bp) {
        #pragma unroll
        for (int ks = 0; ks < 2; ++ks) {
            f16x8 fr[4];
            #pragma unroll
            for (int i2 = 0; i2 < 4; ++i2)
                fr[i2] = *(const f16x8*)(bp + (i2 * 16 + l4) * 128 +
                                         ((ks * 64 + lg * 16) ^ ((l4 & 7) << 4)));
            if (!hi) {
                #pragma unroll
                for (int tj = 0; tj < 4; ++tj) {
                    dd[0][tj] = MF(fr[tj], fr[0], dd[0][tj]);
                    dd[1][tj] = MF(fr[tj], fr[1], dd[1][tj]);
                }
            } else {
                #pragma unroll
                for (int tj = 0; tj < 4; ++tj) {
                    dd[0][tj] = MF(fr[tj], fr[2], dd[0][tj]);
                    dd[1][tj] = MF(fr[tj], fr[3], dd[1][tj]);
                }
            }
        }
    };

    unsigned char* buf0 = XS;
    unsigned char* buf1 = XS + BUF;
    const unsigned char* g0 = buf0 + w4 * SLICE;
    const unsigned char* g1 = buf1 + w4 * SLICE;

    // ---- software pipeline: 4 chunks of 64 t, 1 barrier per chunk ----
    load_chunk(0);
    write_chunk(buf0);        // vmcnt wait here (prologue, unavoidable)
    load_chunk(64);           // chunk1 in flight
    __syncthreads();          // buf0 ready

    gram_buf(g0);             // chunk0
    write_chunk(buf1);        // chunk1 (waits residual vmcnt)
    load_chunk(128);          // chunk2 in flight
    __syncthreads();          // buf1 ready; all buf0 reads done

    gram_buf(g1);             // chunk1
    write_chunk(buf0);        // chunk2
    load_chunk(192);          // chunk3 in flight
    __syncthreads();          // buf0 ready; all buf1 reads done

    gram_buf(g0);             // chunk2
    write_chunk(buf1);        // chunk3
    __syncthreads();          // buf1 ready

    gram_buf(g1);             // chunk3

    // ---- R = diag(G). Diag tiles: dd[0][2hi], dd[1][2hi+1]; lg*4+reg==l4 ----
    {
        f32x4 dg0 = hi ? dd[0][2] : dd[0][0];
        f32x4 dg1 = hi ? dd[1][3] : dd[1][1];
        if (lg == (l4 >> 2)) {
            int r = l4 & 3;
            float v0 = r == 0 ? dg0[0] : r == 1 ? dg0[1] : r == 2 ? dg0[2] : dg0[3];
            float v1 = r == 0 ? dg1[0] : r == 1 ? dg1[1] : r == 2 ? dg1[2] : dg1[3];
            Rbuf[w4][(hi * 2) * 16 + l4] = v0;
            Rbuf[w4][(hi * 2 + 1) * 16 + l4] = v1;
        }
    }
    __syncthreads();   // Rbuf ready; all XS gram reads done (XS reusable)

    // ---- D = R_row + R_col - 2G in place; build 32 u16 keys ----
    float Rr0 = Rbuf[w4][(hi * 2) * 16 + l4];
    float Rr1 = Rbuf[w4][(hi * 2 + 1) * 16 + l4];
    int keys[64];
    #pragma unroll
    for (int tj = 0; tj < 4; ++tj) {
        f32x4 Rc = *(const f32x4*)&Rbuf[w4][tj * 16 + lg * 4];
        #pragma unroll
        for (int r = 0; r < 4; ++r) {
            dd[0][tj][r] = Rr0 + Rc[r] - 2.0f * dd[0][tj][r];
            dd[1][tj][r] = Rr1 + Rc[r] - 2.0f * dd[1][tj][r];
        }
    }
    #pragma unroll
    for (int tt = 0; tt < 2; ++tt) {
        int row = (hi * 2 + tt) * 16 + l4;
        #pragma unroll
        for (int tj = 0; tj < 4; ++tj)
            #pragma unroll
            for (int r = 0; r < 4; ++r) {
                int col = tj * 16 + lg * 4 + r;
                _Float16 hx = (_Float16)fmaxf(dd[tt][tj][r], 0.0f);
                uint16_t kb = __builtin_bit_cast(uint16_t, hx);
                keys[tt * 16 + tj * 4 + r] = (row < col) ? (int)kb : 0x7FFF;
            }
    }

    // ---- one-shot key exchange between the wave pair (reuses XS) ----
    {
        unsigned char* base = XS + w4 * 16384;
        uint16_t* mywr = (uint16_t*)(base + hi * 4096);
        #pragma unroll
        for (int e = 0; e < 32; ++e)
            mywr[e * 64 + lane] = (uint16_t)keys[e];
        __syncthreads();
        const uint16_t* prd = (const uint16_t*)(base + (hi ^ 1) * 4096);
        #pragma unroll
        for (int e = 0; e < 32; ++e)
            keys[32 + e] = (int)prd[e * 64 + lane];
    }

    // ---- exact rank-1008 select on 15-bit f16 keys (redundant per wave) ----
    int u = 0;
    for (int bit = 14; bit >= 0; --bit) {
        int cand = u | (1 << bit);
        int cnt = 0;
        #pragma unroll
        for (int i = 0; i < 64; ++i) cnt += (keys[i] < cand) ? 1 : 0;
        #pragma unroll
        for (int off = 32; off; off >>= 1) cnt += __shfl_xor(cnt, off, 64);
        if (cnt <= 1008) u = cand;
    }
    float sigma2 = (float)__builtin_bit_cast(_Float16, (uint16_t)u);
    float ninv = -1.0f / (2.0f * p10 * sigma2);

    // ---- epilogue: A = exp(-D/denom); float4 stores (4 consecutive cols) ----
    float* op = out + ((size_t)(n * 64 + f0 + w4) << 12);
    #pragma unroll
    for (int tt = 0; tt < 2; ++tt) {
        int row = (hi * 2 + tt) * 16 + l4;
        #pragma unroll
        for (int tj = 0; tj < 4; ++tj) {
            float4 rv;
            rv.x = __expf(dd[tt][tj][0] * ninv);
            rv.y = __expf(dd[tt][tj][1] * ninv);
            rv.z = __expf(dd[tt][tj][2] * ninv);
            rv.w = __expf(dd[tt][tj][3] * ninv);
            *(float4*)(op + row * 64 + tj * 16 + lg * 4) = rv;
        }
    }
}

extern "C" void kernel_launch(void* const* d_in, const int* in_sizes, int n_in,
                              void* d_out, int out_size, void* d_ws, size_t ws_size,
                              hipStream_t stream) {
    (void)in_sizes; (void)n_in; (void)out_size; (void)d_ws; (void)ws_size;
    const float* X  = (const float*)d_in[0];
    const float* gp = (const float*)d_in[1];
    float* out = (float*)d_out;
    gfc_main<<<512, 512, 0, stream>>>(X, gp, out);
}